// Round 14
// baseline (82.697 us; speedup 1.0000x reference)
//
#include <hip/hip_runtime.h>
#include <hip/hip_bf16.h>
#include <hip/hip_fp8.h>

typedef float f32x4 __attribute__((ext_vector_type(4)));
typedef float f32x2 __attribute__((ext_vector_type(2)));
typedef int   i32x4 __attribute__((ext_vector_type(4)));
typedef int   i32x8 __attribute__((ext_vector_type(8)));

static constexpr int D     = 128;
static constexpr int BATCH = 4096;
static constexpr int N     = 8192;
static constexpr int BT    = 128;               // tile
static constexpr int NT    = N / BT;            // 64
static constexpr int TRI   = NT * (NT + 1) / 2; // 2080
static constexpr int SCALE1 = 0x7F7F7F7F;       // e8m0 scale bytes = 1.0

__device__ __forceinline__ void load_lds16(const void* g, void* l) {
    __builtin_amdgcn_global_load_lds(
        (const __attribute__((address_space(1))) unsigned int*)g,
        (__attribute__((address_space(3))) unsigned int*)l, 16, 0, 0);
}

__device__ __forceinline__ f32x2 pkmax1(f32x2 a) {
    return (f32x2){fmaxf(a[0], 1.f), fmaxf(a[1], 1.f)};
}
__device__ __forceinline__ f32x2 pkrcp(f32x2 a) {
    return (f32x2){__builtin_amdgcn_rcpf(a[0]), __builtin_amdgcn_rcpf(a[1])};
}

// ---------------- prep: fp8 Apack (fragment-order) + Bimg (swizzled LDS image) + norms + diag ----------------
// Bimg byte(row r, col k): (r>>7)*16384 + (r&127)*128 + (((k>>4) ^ (r&7))<<4) + (k&15)
// Apack byte(row r, col k): (r>>4)*2048 + (k>>5)*512 + (r&15)*32 + (k&31)   [per-wave A fragments contiguous]
__global__ __launch_bounds__(256) void prep_kernel(const float* __restrict__ f,
                                                   unsigned char* __restrict__ Apack,
                                                   unsigned char* __restrict__ Bimg,
                                                   float* __restrict__ norms,
                                                   float* __restrict__ diag,
                                                   float* __restrict__ out) {
    if (blockIdx.x == 0 && threadIdx.x == 0) out[0] = 0.f;
    const int w = threadIdx.x >> 6, lane = threadIdx.x & 63;
    const int i = blockIdx.x * 4 + w;                 // 0..4095
    const float2 va = *(const float2*)(f + (size_t)i * D + lane * 2);
    const float2 vb = *(const float2*)(f + (size_t)(i + BATCH) * D + lane * 2);

    const int k = lane * 2;                           // column pair this lane owns
    auto storeBoth = [&](int row, float x, float y) {
        union { unsigned char b[2]; unsigned short u; } pk;
        pk.b[0] = __hip_fp8_e4m3(x).__x;
        pk.b[1] = __hip_fp8_e4m3(y).__x;
        const size_t bdst = (size_t)(row >> 7) * 16384 + (row & 127) * 128
                          + (((k >> 4) ^ (row & 7)) << 4) + (k & 14);
        *(unsigned short*)(Bimg + bdst) = pk.u;
        const size_t adst = (size_t)(row >> 4) * 2048 + ((k >> 5) << 9)
                          + ((row & 15) << 5) + (k & 31);
        *(unsigned short*)(Apack + adst) = pk.u;
    };
    storeBoth(i, va.x, va.y);
    storeBoth(i + BATCH, vb.x, vb.y);

    float na = va.x * va.x + va.y * va.y;
    float nb = vb.x * vb.x + vb.y * vb.y;
    const float dx = va.x - vb.x, dy = va.y - vb.y;
    float dd = dx * dx + dy * dy;
    #pragma unroll
    for (int m = 1; m <= 32; m <<= 1) {
        na += __shfl_xor(na, m); nb += __shfl_xor(nb, m); dd += __shfl_xor(dd, m);
    }
    if (lane == 0) {
        norms[i] = na; norms[i + BATCH] = nb;
        diag[i] = 1.f / (dd + 1.f);                   // exact fp32 cauchy diag of sim_ab
    }
}

// ---------------- 128x128 tile: A direct->VGPR, B via LDS, fp8 MX K=128, packed epilogue ----------------
// P[t][k][0..127]: k<=t row-partials of tile(t,k); k>t col-partials of tile(k,t). Exact-once writes.
__global__ __launch_bounds__(256, 4) void tile_kernel(const unsigned char* __restrict__ Apack,
                                                      const unsigned char* __restrict__ Bimg,
                                                      const float* __restrict__ norms,
                                                      float* __restrict__ P) {
    // XCD-chunked bijective swizzle (2080 % 8 == 0)
    const int bid = blockIdx.x;
    const int id = (bid & 7) * (TRI / 8) + (bid >> 3);
    int ti = (int)((sqrtf(8.f * (float)id + 1.f) - 1.f) * 0.5f);
    while ((ti + 1) * (ti + 2) / 2 <= id) ++ti;
    while (ti * (ti + 1) / 2 > id) --ti;
    const int tj = id - ti * (ti + 1) / 2;
    const bool diagblk = (ti == tj);

    __shared__ __align__(16) unsigned char Bs[16384];  // fp8 B panel image (swizzled)
    __shared__ float colbuf[BT];

    const int tid = threadIdx.x, wv = tid >> 6, lane = tid & 63;
    const int lr = lane & 15, hk = lane >> 4;

    // ---- A fragments: direct, coalesced, issued first (latency hides under B-stage) ----
    const unsigned char* Ab = Apack + (size_t)(ti * 8 + wv * 2) * 2048;
    const int ao = hk * 512 + lr * 32;
    const i32x4 a00 = *(const i32x4*)(Ab + ao);
    const i32x4 a01 = *(const i32x4*)(Ab + ao + 16);
    const i32x4 a10 = *(const i32x4*)(Ab + 2048 + ao);
    const i32x4 a11 = *(const i32x4*)(Ab + 2048 + ao + 16);

    if (tid < BT) colbuf[tid] = 0.f;

    // ---- stage B image (16KB, identity copy of swizzled layout) ----
    const unsigned char* Bimg_t = Bimg + (size_t)tj * 16384;
    #pragma unroll
    for (int it = 0; it < 4; ++it)
        load_lds16(Bimg_t + (it * 256 + tid) * 16, Bs + it * 4096 + wv * 1024);
    __syncthreads();

    const i32x8 av0 = __builtin_shufflevector(a00, a01, 0, 1, 2, 3, 4, 5, 6, 7);
    const i32x8 av1 = __builtin_shufflevector(a10, a11, 0, 1, 2, 3, 4, 5, 6, 7);

    // B fragment read: row fj*16+lr, k-chunks (hk*2, hk*2+1) ^ (lr&7)  [conflict-free]
    auto frag = [&](int rowbase) -> i32x8 {
        const int row = rowbase + lr;
        const i32x4 q0 = *(const i32x4*)(Bs + row * 128 + (((hk * 2 + 0) ^ (lr & 7)) << 4));
        const i32x4 q1 = *(const i32x4*)(Bs + row * 128 + (((hk * 2 + 1) ^ (lr & 7)) << 4));
        return __builtin_shufflevector(q0, q1, 0, 1, 2, 3, 4, 5, 6, 7);
    };

    f32x4 acc[2][8];
    #pragma unroll
    for (int i = 0; i < 2; ++i)
        #pragma unroll
        for (int j = 0; j < 8; ++j)
            acc[i][j] = (f32x4){0.f, 0.f, 0.f, 0.f};

    #pragma unroll
    for (int fj = 0; fj < 8; ++fj) {
        const i32x8 bv = frag(fj * 16);
        acc[0][fj] = __builtin_amdgcn_mfma_scale_f32_16x16x128_f8f6f4(
            av0, bv, acc[0][fj], 0, 0, 0, SCALE1, 0, SCALE1);
        acc[1][fj] = __builtin_amdgcn_mfma_scale_f32_16x16x128_f8f6f4(
            av1, bv, acc[1][fj], 0, 0, 0, SCALE1, 0, SCALE1);
    }

    float* PR = P + ((size_t)ti * NT + tj) * BT;

    if (!diagblk) {
        // ---- fast packed epilogue: on-the-fly row+col accumulation, no diag selects ----
        float colN[8];
        #pragma unroll
        for (int fj = 0; fj < 8; ++fj)
            colN[fj] = norms[tj * BT + fj * 16 + lr];

        f32x2 rn[2][2], rs[2][2];
        #pragma unroll
        for (int fi = 0; fi < 2; ++fi) {
            const int lrow = wv * 32 + fi * 16 + hk * 4;
            const f32x4 rN = *(const f32x4*)(norms + ti * BT + lrow);
            rn[fi][0] = (f32x2){rN[0] + 1.f, rN[1] + 1.f};
            rn[fi][1] = (f32x2){rN[2] + 1.f, rN[3] + 1.f};
            rs[fi][0] = (f32x2){0.f, 0.f};
            rs[fi][1] = (f32x2){0.f, 0.f};
        }

        #pragma unroll
        for (int fj = 0; fj < 8; ++fj) {
            const f32x2 cn2 = (f32x2){colN[fj], colN[fj]};
            f32x2 cs = (f32x2){0.f, 0.f};
            #pragma unroll
            for (int fi = 0; fi < 2; ++fi) {
                const f32x2 d01 = (f32x2){acc[fi][fj][0], acc[fi][fj][1]};
                const f32x2 d23 = (f32x2){acc[fi][fj][2], acc[fi][fj][3]};
                const f32x2 s01 = pkrcp(pkmax1(rn[fi][0] + cn2 - 2.f * d01));
                const f32x2 s23 = pkrcp(pkmax1(rn[fi][1] + cn2 - 2.f * d23));
                rs[fi][0] += s01; rs[fi][1] += s23;
                cs += s01 + s23;
            }
            float csf = cs[0] + cs[1];
            csf += __shfl_xor(csf, 16);
            csf += __shfl_xor(csf, 32);
            if (hk == 0)
                atomicAdd(&colbuf[fj * 16 + lr], csf);
        }

        #pragma unroll
        for (int fi = 0; fi < 2; ++fi) {
            f32x4 rsv = (f32x4){rs[fi][0][0], rs[fi][0][1], rs[fi][1][0], rs[fi][1][1]};
            #pragma unroll
            for (int r = 0; r < 4; ++r) {
                rsv[r] += __shfl_xor(rsv[r], 1);
                rsv[r] += __shfl_xor(rsv[r], 2);
                rsv[r] += __shfl_xor(rsv[r], 4);
                rsv[r] += __shfl_xor(rsv[r], 8);
            }
            if (lr == 0)
                *(f32x4*)(PR + wv * 32 + fi * 16 + hk * 4) = rsv;  // exact-once row writes
        }

        __syncthreads();
        if (tid < BT)
            P[((size_t)tj * NT + ti) * BT + tid] = colbuf[tid];    // exact-once col writes
    } else {
        // ---- diag path (64 blocks): scalar with self-mask; rows only ----
        float colN[8];
        #pragma unroll
        for (int fj = 0; fj < 8; ++fj)
            colN[fj] = norms[tj * BT + fj * 16 + lr];
        #pragma unroll
        for (int fi = 0; fi < 2; ++fi) {
            const int lrow = wv * 32 + fi * 16 + hk * 4;
            const f32x4 rN = *(const f32x4*)(norms + ti * BT + lrow);
            f32x4 rsv = (f32x4){0.f, 0.f, 0.f, 0.f};
            #pragma unroll
            for (int fj = 0; fj < 8; ++fj) {
                const int lcol = fj * 16 + lr;
                #pragma unroll
                for (int r = 0; r < 4; ++r) {
                    float sq = rN[r] + colN[fj] - 2.f * acc[fi][fj][r];
                    sq = fmaxf(sq, 0.f);
                    float sim = __builtin_amdgcn_rcpf(sq + 1.f);
                    if (lrow + r == lcol) sim = 0.f;               // self-mask
                    rsv[r] += sim;
                }
            }
            #pragma unroll
            for (int r = 0; r < 4; ++r) {
                rsv[r] += __shfl_xor(rsv[r], 1);
                rsv[r] += __shfl_xor(rsv[r], 2);
                rsv[r] += __shfl_xor(rsv[r], 4);
                rsv[r] += __shfl_xor(rsv[r], 8);
            }
            if (lr == 0)
                *(f32x4*)(PR + lrow) = rsv;
        }
    }
}

// ---------------- finalize: uniform 64-slot sum per row, logs, scalar ----------------
__global__ __launch_bounds__(128) void finalize_kernel(const float* __restrict__ P,
                                                       const float* __restrict__ diag,
                                                       float* __restrict__ out) {
    const int t = blockIdx.x;            // 64 row-panels
    const int r = threadIdx.x;           // 128 rows per panel
    const float* base = P + (size_t)t * NT * BT + r;
    float s = 0.f;
    #pragma unroll 8
    for (int k = 0; k < NT; ++k) s += base[k * BT];
    const int i = t * BT + r;
    float term = 0.5f * __logf(s);
    if (i >= BATCH) term -= __logf(diag[i - BATCH]);
    #pragma unroll
    for (int m = 1; m <= 32; m <<= 1) term += __shfl_xor(term, m);
    if ((threadIdx.x & 63) == 0)
        atomicAdd(out, term / (float)BATCH);
}

extern "C" void kernel_launch(void* const* d_in, const int* in_sizes, int n_in,
                              void* d_out, int out_size, void* d_ws, size_t ws_size,
                              hipStream_t stream) {
    const float* feat = (const float*)d_in[0];
    char* ws = (char*)d_ws;
    // ws layout: Apack 1MB @0 | Bimg 1MB @1MB | norms 32KB @2MB | diag 16KB | P 2MB
    unsigned char* Apack = (unsigned char*)ws;
    unsigned char* Bimg  = (unsigned char*)(ws + (1u << 20));
    float* norms = (float*)(ws + (2u << 20));
    float* diag  = (float*)(ws + (2u << 20) + 32768);
    float* P     = (float*)(ws + (2u << 20) + 49152);
    float* out   = (float*)d_out;

    prep_kernel<<<BATCH / 4, 256, 0, stream>>>(feat, Apack, Bimg, norms, diag, out);
    tile_kernel<<<TRI, 256, 0, stream>>>(Apack, Bimg, norms, P);
    finalize_kernel<<<NT, 128, 0, stream>>>(P, diag, out);
}